// Round 5
// baseline (280.973 us; speedup 1.0000x reference)
//
#include <hip/hip_runtime.h>
#include <cstdint>

// ---------------- problem constants ----------------
#define BB 8
#define SS 2048
#define DD 1024
#define HH 16
#define HDIM 64
#define MTOT (BB*SS)          // 16384
#define NQKV 3072

typedef __attribute__((ext_vector_type(8))) __bf16 bf16x8;
typedef __attribute__((ext_vector_type(4))) float f32x4;

#define AS1(p) ((const __attribute__((address_space(1))) void*)(p))
#define AS3(p) ((__attribute__((address_space(3))) void*)(p))

__device__ __forceinline__ float bf2f(uint16_t u){
  return __uint_as_float(((uint32_t)u) << 16);
}
__device__ __forceinline__ uint16_t f2bf(float f){
  uint32_t u = __float_as_uint(f);
  return (uint16_t)((u + 0x7fffu + ((u >> 16) & 1u)) >> 16);
}

// ---------------- merged prep kernel ----------------
__global__ __launch_bounds__(256)
void k_prep(const float* __restrict__ x,
            const float* __restrict__ Wq, const float* __restrict__ Wk,
            const float* __restrict__ Wv, const float* __restrict__ Wo,
            const float* __restrict__ bq, const float* __restrict__ bk,
            const float* __restrict__ bv,
            uint16_t* __restrict__ xb, uint16_t* __restrict__ Wt,
            uint16_t* __restrict__ WoT, float* __restrict__ bqkv)
{
  __shared__ float t[32][33];
  const int blk = blockIdx.x, tid = threadIdx.x;
  if (blk < 2048){
    const int n4 = MTOT*DD/4;
    for (int i = blk*256 + tid; i < n4; i += 2048*256){
      float4 v = reinterpret_cast<const float4*>(x)[i];
      ushort4 o;
      o.x = f2bf(v.x); o.y = f2bf(v.y); o.z = f2bf(v.z); o.w = f2bf(v.w);
      reinterpret_cast<ushort4*>(xb)[i] = o;
    }
  } else if (blk < 6144){
    const int zb = blk - 2048;
    const int z = zb >> 10, rem = zb & 1023;
    const int by = rem >> 5, bx = rem & 31;
    const float* src = (z==0)?Wq:(z==1)?Wk:(z==2)?Wv:Wo;
    uint16_t* dst = (z<3) ? (Wt + (size_t)z*1024*1024) : WoT;
    const int k0 = by*32, n0 = bx*32;
    const int tx = tid & 31, ty = tid >> 5;
    #pragma unroll
    for (int r = 0; r < 4; ++r)
      t[ty + r*8][tx] = src[(size_t)(k0 + ty + r*8)*1024 + n0 + tx];
    __syncthreads();
    #pragma unroll
    for (int r = 0; r < 4; ++r)
      dst[(size_t)(n0 + ty + r*8)*1024 + k0 + tx] = f2bf(t[tx][ty + r*8]);
  } else {
    const int i = (blk - 6144)*256 + tid;
    if (i < NQKV)
      bqkv[i] = (i < 1024) ? bq[i] : (i < 2048) ? bk[i-1024] : bv[i-2048];
  }
}

// ============ 256x256 pipelined-read 8-window GEMM: C = A[M][1024]*Bt[N][1024]^T ======
// 8 waves (2Mx4N), BK=64, K=1024 fully unrolled. 128KiB LDS double-buffer, XOR
// swizzle both sides (T2), XCD swizzle (T1), setprio (T5).
// NEW: register loads pipelined one window ahead (READ(p+1-data); MMA(p); STAGE; BAR).
// Ping-pong fragment regs aP/aQ, bP/bQ (period-8 rotation, all-static indices).
// vmcnt(4) BEFORE a barrier at windows 4/8 (completes exactly the buffer about to be
// read: 12 outstanding -> drain 8). 10 barriers/iter (was 16).
// EPI 0: out bf16 = acc + bias[col]; EPI 1: += bf16 resid.

#define BARRIER __builtin_amdgcn_s_barrier()
#define VMCNT4  asm volatile("s_waitcnt vmcnt(4)" ::: "memory")
#define VMCNT0  asm volatile("s_waitcnt vmcnt(0)" ::: "memory")

#define READA_(BUF, MH, DST) { \
  const uint16_t* _sl = lds + ((BUF)*4 + (MH))*8192; \
  _Pragma("unroll") \
  for (int f = 0; f < 4; ++f) \
    _Pragma("unroll") \
    for (int ks = 0; ks < 2; ++ks) \
      DST[f][ks] = *(const bf16x8*)(_sl + (wm*64 + f*16 + l15)*64 + (((ks*4 + l4) ^ l7)<<3)); \
}

#define READB_(BUF, NH, DST) { \
  const uint16_t* _sl = lds + ((BUF)*4 + 2 + (NH))*8192; \
  _Pragma("unroll") \
  for (int j = 0; j < 2; ++j) \
    _Pragma("unroll") \
    for (int ks = 0; ks < 2; ++ks) \
      DST[j][ks] = *(const bf16x8*)(_sl + (wn*32 + j*16 + l15)*64 + (((ks*4 + l4) ^ l7)<<3)); \
}

#define MMA_(MH, NH, AV, BV) { \
  __builtin_amdgcn_s_setprio(1); \
  _Pragma("unroll") \
  for (int ks = 0; ks < 2; ++ks) \
    _Pragma("unroll") \
    for (int f = 0; f < 4; ++f) \
      _Pragma("unroll") \
      for (int j = 0; j < 2; ++j) \
        acc[(MH)*4+f][(NH)*2+j] = __builtin_amdgcn_mfma_f32_16x16x32_bf16(AV[f][ks], BV[j][ks], acc[(MH)*4+f][(NH)*2+j], 0, 0, 0); \
  __builtin_amdgcn_s_setprio(0); }

#define STAGEA(T, H) { \
  char* _d = (char*)lds + ((((T)&1)*4 + (H))*16384) + wave*1024; \
  _Pragma("unroll") \
  for (int l = 0; l < 2; ++l) \
    __builtin_amdgcn_global_load_lds(AS1(pA + (l*131072 + (H)*65536 + (T)*64)), AS3(_d + l*8192), 16, 0, 0); \
}

#define STAGEB(T, H) { \
  char* _d = (char*)lds + ((((T)&1)*4 + 2 + (H))*16384) + wave*1024; \
  _Pragma("unroll") \
  for (int l = 0; l < 2; ++l) \
    __builtin_amdgcn_global_load_lds(AS1(pB + (l*131072 + (H)*32768 + (T)*64)), AS3(_d + l*8192), 16, 0, 0); \
}

template<int EPI, int NB_T>
__global__ __launch_bounds__(512)
void k_gemm256(const uint16_t* __restrict__ A, const uint16_t* __restrict__ Bt,
               const float* __restrict__ bias, const uint16_t* __restrict__ resid16,
               uint16_t* __restrict__ Cout)
{
  constexpr int N = NB_T * 256;
  __shared__ uint16_t lds[8 * 8192];   // 128 KiB
  const int tid = threadIdx.x;
  const int lane = tid & 63, wave = tid >> 6;
  const int wm = wave >> 2, wn = wave & 3;     // 2 M-waves x 4 N-waves
  const int l15 = lane & 15, l4 = lane >> 4, l7 = lane & 7;

  // T1: bijective XCD swizzle (grid % 8 == 0)
  const int nwg = gridDim.x, cpx = nwg >> 3, bid = blockIdx.x;
  const int wg = (bid & 7) * cpx + (bid >> 3);
  const int m0 = (wg / NB_T) << 8, n0 = (wg % NB_T) << 8;

  // per-lane staging base pointers (swizzled source column)
  const int colbase = (((tid & 7) ^ ((tid >> 3) & 7)) << 3);
  const uint16_t* pA = A  + (size_t)(m0 + (tid >> 3)) * 1024 + colbase;
  const uint16_t* pB = Bt + (size_t)(n0 + ((tid >> 8) << 6) + ((tid >> 3) & 31)) * 1024 + colbase;

  f32x4 acc[8][4] = {};       // [mh*4+f][nh*2+j]
  bf16x8 aP[4][2], aQ[4][2];  // A-half fragments (ping-pong)
  bf16x8 bP[2][2], bQ[2][2];  // B-half fragments (rotating roles)

  // ---- prologue: kt0 all 4 halves + kt1 {A0,B1}; vmcnt(4) lands kt0; stage kt1 A1
  STAGEA(0,0); STAGEB(0,1); STAGEA(0,1); STAGEB(0,0);
  STAGEA(1,0); STAGEB(1,1);
  VMCNT4;                 // 12 outstanding -> drain 8 = all of kt0
  STAGEA(1,1);            // in flight: {A(1,0), B(1,1), A(1,1)} = 6
  BARRIER;
  READA_(0,0,aP); READB_(0,0,bP);   // fragments for window 1's MMA

  #pragma unroll
  for (int I = 0; I < 7; ++I){
    const int e = 2*I;
    // W1: MMA(0,0)buf0 [aP,bP]; read B1(buf0)->bQ; stage B(e+1,0)
    READB_(0,1,bQ); STAGEB(e+1,0); MMA_(0,0,aP,bP); BARRIER;
    // W2: MMA(0,1) [aP,bQ]; read A1(buf0)->aQ; stage A(e+2,0)
    READA_(0,1,aQ); STAGEA(e+2,0); MMA_(0,1,aP,bQ); BARRIER;
    // W3: MMA(1,1) [aQ,bQ]; stage B(e+2,1)
    STAGEB(e+2,1); MMA_(1,1,aQ,bQ); BARRIER;
    // W4: vmcnt(4) lands buf1; barrier; read A0,B0(buf1)->aP,bQ; MMA(1,0)[aQ,bP]; stage A(e+2,1)
    VMCNT4; BARRIER;
    READA_(1,0,aP); READB_(1,0,bQ); STAGEA(e+2,1); MMA_(1,0,aQ,bP); BARRIER;
    // W5: MMA(0,0)buf1 [aP,bQ]; read B1(buf1)->bP; stage B(e+2,0)
    READB_(1,1,bP); STAGEB(e+2,0); MMA_(0,0,aP,bQ); BARRIER;
    // W6: MMA(0,1) [aP,bP]; read A1(buf1)->aQ; stage A(e+3,0)
    READA_(1,1,aQ); STAGEA(e+3,0); MMA_(0,1,aP,bP); BARRIER;
    // W7: MMA(1,1) [aQ,bP]; stage B(e+3,1)
    STAGEB(e+3,1); MMA_(1,1,aQ,bP); BARRIER;
    // W8: vmcnt(4) lands next buf0; barrier; read A0,B0(buf0')->aP,bP; MMA(1,0)[aQ,bQ]; stage A(e+3,1)
    VMCNT4; BARRIER;
    READA_(0,0,aP); READB_(0,0,bP); STAGEA(e+3,1); MMA_(1,0,aQ,bQ); BARRIER;
  }

  { // ---- epilogue: kt 14 (buf0), kt 15 (buf1); only B(15,0) left to stage
    READB_(0,1,bQ); STAGEB(15,0); MMA_(0,0,aP,bP); BARRIER;
    READA_(0,1,aQ); MMA_(0,1,aP,bQ); BARRIER;
    MMA_(1,1,aQ,bQ); BARRIER;
    VMCNT0; BARRIER;
    READA_(1,0,aP); READB_(1,0,bQ); MMA_(1,0,aQ,bP); BARRIER;
    READB_(1,1,bP); MMA_(0,0,aP,bQ); BARRIER;
    READA_(1,1,aQ); MMA_(0,1,aP,bP); BARRIER;
    MMA_(1,1,aQ,bP); BARRIER;
    MMA_(1,0,aQ,bQ);
  }

  // ---- C-write
  #pragma unroll
  for (int mh = 0; mh < 2; ++mh)
  #pragma unroll
  for (int f = 0; f < 4; ++f)
  #pragma unroll
  for (int nh = 0; nh < 2; ++nh)
  #pragma unroll
  for (int j = 0; j < 2; ++j){
    const int gcol = n0 + wn*64 + nh*32 + j*16 + l15;
    const float bi = bias[gcol];
    const int rbase = m0 + wm*128 + mh*64 + f*16 + l4*4;
    #pragma unroll
    for (int rr = 0; rr < 4; ++rr){
      const size_t idx = (size_t)(rbase + rr)*N + gcol;
      float v = acc[mh*4+f][nh*2+j][rr] + bi;
      if (EPI == 1) v += bf2f(resid16[idx]);
      Cout[idx] = f2bf(v);
    }
  }
}

// ---------------- per-(b,h) pooling kernel (512 threads, 8 waves) ----------------
__device__ __forceinline__ float block_red_max512(float v, float* red, int tid){
  red[tid] = v; __syncthreads();
  for (int off = 256; off > 0; off >>= 1){
    if (tid < off) red[tid] = fmaxf(red[tid], red[tid+off]);
    __syncthreads();
  }
  float r = red[0]; __syncthreads();
  return r;
}
__device__ __forceinline__ float block_red_sum512(float v, float* red, int tid){
  red[tid] = v; __syncthreads();
  for (int off = 256; off > 0; off >>= 1){
    if (tid < off) red[tid] += red[tid+off];
    __syncthreads();
  }
  float r = red[0]; __syncthreads();
  return r;
}

__device__ __forceinline__ void score_pass(const uint16_t* __restrict__ base,
    float biasv, const float* wv, float* sc, const float* __restrict__ mrow, int tid){
  for (int s = tid; s < SS; s += 512){
    const uint16_t* row = base + (size_t)s*NQKV;
    float acc = 0.f;
    #pragma unroll
    for (int jj = 0; jj < 8; ++jj){
      int4 raw = *(const int4*)(row + jj*8);
      unsigned uu[4] = {(unsigned)raw.x,(unsigned)raw.y,(unsigned)raw.z,(unsigned)raw.w};
      #pragma unroll
      for (int e = 0; e < 4; ++e){
        acc += __uint_as_float(uu[e] << 16)        * wv[jj*8 + 2*e]
             + __uint_as_float(uu[e] & 0xffff0000u) * wv[jj*8 + 2*e + 1];
      }
    }
    sc[s] = (acc + biasv)*0.125f + mrow[s];
  }
}

__device__ __forceinline__ void col_accum(const uint16_t* __restrict__ base,
    const float* sc, float part[8][64], int tid){
  const int j = tid & 63, g = tid >> 6;   // 8 groups x 256 rows
  const uint16_t* p = base + (size_t)(g*256)*NQKV + j;
  float a = 0.f;
  for (int s = 0; s < 256; ++s)
    a += sc[g*256 + s] * bf2f(p[(size_t)s*NQKV]);
  part[g][j] = a;
}

__global__ __launch_bounds__(512)
void k_head(const uint16_t* __restrict__ qkv, const float* __restrict__ mask,
            const float* __restrict__ wa, const float* __restrict__ ba,
            const float* __restrict__ wb, const float* __restrict__ bbp,
            const float* __restrict__ Wu, uint16_t* __restrict__ WuPT)
{
  __shared__ float sc[SS];
  __shared__ float red[512];
  __shared__ float part[8][64];
  __shared__ float qav[64];
  __shared__ float wvec[64];
  __shared__ float pav[64];

  const int bh = blockIdx.x, b = bh >> 4, h = bh & 15;
  const int tid = threadIdx.x;
  const uint16_t* qb  = qkv + (size_t)b*SS*NQKV + h*64;
  const uint16_t* kb2 = qb + 1024;
  const float* mrow = mask + b*SS;

  if (tid < 64) wvec[tid] = wa[tid];
  __syncthreads();

  // ---- alpha ----
  score_pass(qb, ba[0], wvec, sc, mrow, tid);
  __syncthreads();
  float lm = -3.4e38f;
  for (int s = tid; s < SS; s += 512) lm = fmaxf(lm, sc[s]);
  float mx = block_red_max512(lm, red, tid);
  float ls = 0.f;
  for (int s = tid; s < SS; s += 512){ float e = __expf(sc[s]-mx); sc[s] = e; ls += e; }
  __syncthreads();
  float inv = 1.f / block_red_sum512(ls, red, tid);

  col_accum(qb, sc, part, tid);
  __syncthreads();
  if (tid < 64){
    float q = 0.f;
    #pragma unroll
    for (int g = 0; g < 8; ++g) q += part[g][tid];
    qav[tid] = q*inv;
    wvec[tid] = q*inv*wb[tid];
  }
  __syncthreads();

  // ---- beta ----
  score_pass(kb2, bbp[0], wvec, sc, mrow, tid);
  __syncthreads();
  lm = -3.4e38f;
  for (int s = tid; s < SS; s += 512) lm = fmaxf(lm, sc[s]);
  mx = block_red_max512(lm, red, tid);
  ls = 0.f;
  for (int s = tid; s < SS; s += 512){ float e = __expf(sc[s]-mx); sc[s] = e; ls += e; }
  __syncthreads();
  float inv2 = 1.f / block_red_sum512(ls, red, tid);

  col_accum(kb2, sc, part, tid);
  __syncthreads();
  if (tid < 64){
    float p = 0.f;
    #pragma unroll
    for (int g = 0; g < 8; ++g) p += part[g][tid];
    pav[tid] = qav[tid]*p*inv2;
  }
  __syncthreads();

  // WuPT[j][i] = pav[i]*Wu[i][j]   (bf16, n-major for MFMA B operand)
  uint16_t* dst = WuPT + (size_t)bh*4096;
  for (int idx = tid; idx < 4096; idx += 512){
    const int i = idx & 63, jcol = idx >> 6;
    dst[idx] = f2bf(pav[i]*Wu[i*64 + jcol]);
  }
}

// ---------------- newr = v @ WuP + bu + q   (per-head MFMA) ----------------
__global__ __launch_bounds__(256)
void k_newr(const uint16_t* __restrict__ qkv, const uint16_t* __restrict__ WuPT,
            const float* __restrict__ bu, uint16_t* __restrict__ newr)
{
  const int bh = blockIdx.x >> 3, st = blockIdx.x & 7;
  const int b = bh >> 4, h = bh & 15;
  const int tid = threadIdx.x, wave = tid >> 6, lane = tid & 63;
  const int l15 = lane & 15, l4 = lane >> 4;
  const int s0 = st*256 + wave*64;
  const uint16_t* vb = qkv + 2048 + h*64;
  const uint16_t* wt = WuPT + (size_t)bh*4096;

  f32x4 acc[4][4] = {};
  #pragma unroll
  for (int ks = 0; ks < 2; ++ks){
    bf16x8 bfr[4];
    #pragma unroll
    for (int n = 0; n < 4; ++n)
      bfr[n] = *(const bf16x8*)(wt + (n*16 + l15)*64 + ks*32 + l4*8);
    #pragma unroll
    for (int m = 0; m < 4; ++m){
      const int s = s0 + m*16 + l15;
      bf16x8 af = *(const bf16x8*)(vb + (size_t)(b*SS + s)*NQKV + ks*32 + l4*8);
      #pragma unroll
      for (int n = 0; n < 4; ++n)
        acc[m][n] = __builtin_amdgcn_mfma_f32_16x16x32_bf16(af, bfr[n], acc[m][n], 0, 0, 0);
    }
  }
  #pragma unroll
  for (int n = 0; n < 4; ++n){
    const int j = n*16 + l15;
    const float bj = bu[j];
    #pragma unroll
    for (int m = 0; m < 4; ++m){
      #pragma unroll
      for (int r = 0; r < 4; ++r){
        const int s = s0 + m*16 + l4*4 + r;
        const size_t qidx = (size_t)(b*SS + s)*NQKV + h*64 + j;
        const float q = bf2f(qkv[qidx]);
        newr[(size_t)(b*SS + s)*DD + h*64 + j] = f2bf(acc[m][n][r] + bj + q);
      }
    }
  }
}

// ---------------- layernorm (bf16 input h, f32 output) ----------------
__global__ __launch_bounds__(256)
void k_ln(const uint16_t* __restrict__ h16, const float* __restrict__ gamma,
          const float* __restrict__ beta, float* __restrict__ out)
{
  __shared__ float r1[256], r2[256];
  const int row = blockIdx.x, tid = threadIdx.x;
  const ushort4 hv = ((const ushort4*)(h16 + (size_t)row*DD))[tid];
  float v0 = bf2f(hv.x), v1 = bf2f(hv.y), v2 = bf2f(hv.z), v3 = bf2f(hv.w);
  float s  = v0 + v1 + v2 + v3;
  float ss = v0*v0 + v1*v1 + v2*v2 + v3*v3;
  r1[tid] = s; r2[tid] = ss; __syncthreads();
  for (int off = 128; off > 0; off >>= 1){
    if (tid < off){ r1[tid] += r1[tid+off]; r2[tid] += r2[tid+off]; }
    __syncthreads();
  }
  const float mu  = r1[0]*(1.f/1024.f);
  const float var = r2[0]*(1.f/1024.f) - mu*mu;
  const float inv = rsqrtf(var + 1e-6f);
  const float4 g  = ((const float4*)gamma)[tid];
  const float4 be = ((const float4*)beta)[tid];
  float4 o;
  o.x = (v0-mu)*inv*g.x + be.x;
  o.y = (v1-mu)*inv*g.y + be.y;
  o.z = (v2-mu)*inv*g.z + be.z;
  o.w = (v3-mu)*inv*g.w + be.w;
  ((float4*)(out + (size_t)row*DD))[tid] = o;
}

// ---------------- launch ----------------
extern "C" void kernel_launch(void* const* d_in, const int* in_sizes, int n_in,
                              void* d_out, int out_size, void* d_ws, size_t ws_size,
                              hipStream_t stream) {
  const float* x    = (const float*)d_in[0];
  const float* mask = (const float*)d_in[1];
  const float* Wq   = (const float*)d_in[2];
  const float* bq   = (const float*)d_in[3];
  const float* Wk   = (const float*)d_in[4];
  const float* bk   = (const float*)d_in[5];
  const float* Wv   = (const float*)d_in[6];
  const float* bv   = (const float*)d_in[7];
  const float* wa   = (const float*)d_in[8];
  const float* ba   = (const float*)d_in[9];
  const float* wb   = (const float*)d_in[10];
  const float* bb   = (const float*)d_in[11];
  const float* Wu   = (const float*)d_in[12];
  const float* bu   = (const float*)d_in[13];
  const float* Wo   = (const float*)d_in[14];
  const float* bo   = (const float*)d_in[15];
  const float* gamma= (const float*)d_in[16];
  const float* beta = (const float*)d_in[17];
  float* out = (float*)d_out;

  char* ws = (char*)d_ws;
  const size_t MB = 1ull << 20;
  uint16_t* xb    = (uint16_t*)(ws);              // 32 MB [16384][1024] bf16
  uint16_t* Wt    = (uint16_t*)(ws + 32*MB);      // 6 MB  [3072][1024]  bf16
  uint16_t* WoT   = (uint16_t*)(ws + 38*MB);      // 2 MB  [1024][1024]  bf16
  float*    bqkv  = (float*)   (ws + 40*MB);      // 12 KB
  uint16_t* WuPT  = (uint16_t*)(ws + 41*MB);      // 1 MB  [128][64][64] bf16
  uint16_t* qkv   = (uint16_t*)(ws + 42*MB);      // 96 MB [16384][3072] bf16
  uint16_t* newr  = (uint16_t*)(ws + 138*MB);     // 32 MB [16384][1024] bf16
  uint16_t* hbuf16= (uint16_t*)(ws + 42*MB);      // 32 MB, aliases dead qkv

  k_prep<<<6156, 256, 0, stream>>>(x, Wq, Wk, Wv, Wo, bq, bk, bv, xb, Wt, WoT, bqkv);

  k_gemm256<0,12><<<(MTOT/256)*(NQKV/256), 512, 0, stream>>>(xb, Wt, bqkv, nullptr, qkv);
  k_head<<<BB*HH, 512, 0, stream>>>(qkv, mask, wa, ba, wb, bb, Wu, WuPT);
  k_newr<<<BB*HH*8, 256, 0, stream>>>(qkv, WuPT, bu, newr);
  k_gemm256<1,4><<<(MTOT/256)*(DD/256), 512, 0, stream>>>(newr, WoT, bo, xb, hbuf16);
  k_ln<<<MTOT, 256, 0, stream>>>(hbuf16, gamma, beta, out);
}

// Round 6
// 229.835 us; speedup vs baseline: 1.2225x; 1.2225x over previous
//
#include <hip/hip_runtime.h>
#include <cstdint>

// ---------------- problem constants ----------------
#define BB 8
#define SS 2048
#define DD 1024
#define HH 16
#define HDIM 64
#define MTOT (BB*SS)          // 16384
#define NQKV 3072

typedef __attribute__((ext_vector_type(8))) __bf16 bf16x8;
typedef __attribute__((ext_vector_type(4))) float f32x4;

#define AS1(p) ((const __attribute__((address_space(1))) void*)(p))
#define AS3(p) ((__attribute__((address_space(3))) void*)(p))

__device__ __forceinline__ float bf2f(uint16_t u){
  return __uint_as_float(((uint32_t)u) << 16);
}
__device__ __forceinline__ uint16_t f2bf(float f){
  uint32_t u = __float_as_uint(f);
  return (uint16_t)((u + 0x7fffu + ((u >> 16) & 1u)) >> 16);
}

// ---------------- merged prep kernel ----------------
__global__ __launch_bounds__(256)
void k_prep(const float* __restrict__ x,
            const float* __restrict__ Wq, const float* __restrict__ Wk,
            const float* __restrict__ Wv, const float* __restrict__ Wo,
            const float* __restrict__ bq, const float* __restrict__ bk,
            const float* __restrict__ bv,
            uint16_t* __restrict__ xb, uint16_t* __restrict__ Wt,
            uint16_t* __restrict__ WoT, float* __restrict__ bqkv)
{
  __shared__ float t[32][33];
  const int blk = blockIdx.x, tid = threadIdx.x;
  if (blk < 2048){
    const int n4 = MTOT*DD/4;
    for (int i = blk*256 + tid; i < n4; i += 2048*256){
      float4 v = reinterpret_cast<const float4*>(x)[i];
      ushort4 o;
      o.x = f2bf(v.x); o.y = f2bf(v.y); o.z = f2bf(v.z); o.w = f2bf(v.w);
      reinterpret_cast<ushort4*>(xb)[i] = o;
    }
  } else if (blk < 6144){
    const int zb = blk - 2048;
    const int z = zb >> 10, rem = zb & 1023;
    const int by = rem >> 5, bx = rem & 31;
    const float* src = (z==0)?Wq:(z==1)?Wk:(z==2)?Wv:Wo;
    uint16_t* dst = (z<3) ? (Wt + (size_t)z*1024*1024) : WoT;
    const int k0 = by*32, n0 = bx*32;
    const int tx = tid & 31, ty = tid >> 5;
    #pragma unroll
    for (int r = 0; r < 4; ++r)
      t[ty + r*8][tx] = src[(size_t)(k0 + ty + r*8)*1024 + n0 + tx];
    __syncthreads();
    #pragma unroll
    for (int r = 0; r < 4; ++r)
      dst[(size_t)(n0 + ty + r*8)*1024 + k0 + tx] = f2bf(t[tx][ty + r*8]);
  } else {
    const int i = (blk - 6144)*256 + tid;
    if (i < NQKV)
      bqkv[i] = (i < 1024) ? bq[i] : (i < 2048) ? bk[i-1024] : bv[i-2048];
  }
}

// ============ 256x256 8-phase GEMM (R4 schedule): C = A[M][1024]*Bt[N][1024]^T ======
// 8 waves (2Mx4N), BK=64, K=1024 fully unrolled, 128KiB LDS double-buffer,
// XOR swizzle both sides (T2), XCD swizzle (T1), setprio (T5), vmcnt(6) (T3+T4).
// Change vs R4: no explicit lgkmcnt(0)/sched_barrier pin — ds_reads are IR-level
// loads, compiler emits fine-grained lgkmcnt(N) before dependent MFMAs.
// EPI 0: out bf16 = acc + bias[col]; EPI 1: += bf16 resid.

#define BARRIER __builtin_amdgcn_s_barrier()

#define READA(BUF, MH) { \
  const uint16_t* _sl = lds + ((BUF)*4 + (MH))*8192; \
  _Pragma("unroll") \
  for (int f = 0; f < 4; ++f) \
    _Pragma("unroll") \
    for (int ks = 0; ks < 2; ++ks) \
      a[f][ks] = *(const bf16x8*)(_sl + (wm*64 + f*16 + l15)*64 + (((ks*4 + l4) ^ l7)<<3)); \
}

#define READB(BUF, NH, BV) { \
  const uint16_t* _sl = lds + ((BUF)*4 + 2 + (NH))*8192; \
  _Pragma("unroll") \
  for (int j = 0; j < 2; ++j) \
    _Pragma("unroll") \
    for (int ks = 0; ks < 2; ++ks) \
      BV[j][ks] = *(const bf16x8*)(_sl + (wn*32 + j*16 + l15)*64 + (((ks*4 + l4) ^ l7)<<3)); \
}

#define MMA(MH, NH, BV) { \
  __builtin_amdgcn_s_setprio(1); \
  _Pragma("unroll") \
  for (int ks = 0; ks < 2; ++ks) \
    _Pragma("unroll") \
    for (int f = 0; f < 4; ++f) \
      _Pragma("unroll") \
      for (int j = 0; j < 2; ++j) \
        acc[(MH)*4+f][(NH)*2+j] = __builtin_amdgcn_mfma_f32_16x16x32_bf16(a[f][ks], BV[j][ks], acc[(MH)*4+f][(NH)*2+j], 0, 0, 0); \
  __builtin_amdgcn_s_setprio(0); }

#define STAGEA(T, H) { \
  char* _d = (char*)lds + ((((T)&1)*4 + (H))*16384) + wave*1024; \
  _Pragma("unroll") \
  for (int l = 0; l < 2; ++l) \
    __builtin_amdgcn_global_load_lds(AS1(pA + (l*131072 + (H)*65536 + (T)*64)), AS3(_d + l*8192), 16, 0, 0); \
}

#define STAGEB(T, H) { \
  char* _d = (char*)lds + ((((T)&1)*4 + 2 + (H))*16384) + wave*1024; \
  _Pragma("unroll") \
  for (int l = 0; l < 2; ++l) \
    __builtin_amdgcn_global_load_lds(AS1(pB + (l*131072 + (H)*32768 + (T)*64)), AS3(_d + l*8192), 16, 0, 0); \
}

template<int EPI, int NB_T>
__global__ __launch_bounds__(512)
void k_gemm256(const uint16_t* __restrict__ A, const uint16_t* __restrict__ Bt,
               const float* __restrict__ bias, const uint16_t* __restrict__ resid16,
               uint16_t* __restrict__ Cout)
{
  constexpr int N = NB_T * 256;
  __shared__ uint16_t lds[8 * 8192];   // 128 KiB
  const int tid = threadIdx.x;
  const int lane = tid & 63, wave = tid >> 6;
  const int wm = wave >> 2, wn = wave & 3;     // 2 M-waves x 4 N-waves
  const int l15 = lane & 15, l4 = lane >> 4, l7 = lane & 7;

  // T1: bijective XCD swizzle (grid % 8 == 0)
  const int nwg = gridDim.x, cpx = nwg >> 3, bid = blockIdx.x;
  const int wg = (bid & 7) * cpx + (bid >> 3);
  const int m0 = (wg / NB_T) << 8, n0 = (wg % NB_T) << 8;

  // per-lane staging base pointers (swizzled source column)
  const int colbase = (((tid & 7) ^ ((tid >> 3) & 7)) << 3);
  const uint16_t* pA = A  + (size_t)(m0 + (tid >> 3)) * 1024 + colbase;
  const uint16_t* pB = Bt + (size_t)(n0 + ((tid >> 8) << 6) + ((tid >> 3) & 31)) * 1024 + colbase;

  f32x4 acc[8][4] = {};     // [mh*4+f][nh*2+j]
  bf16x8 a[4][2], b0[2][2], b1[2][2];

  // ---- prologue: tile0 (all 4 halves) + tile1 (A0,B1,A1); tile1's 3 left in flight
  STAGEA(0,0); STAGEB(0,1); STAGEA(0,1); STAGEB(0,0);
  STAGEA(1,0); STAGEB(1,1); STAGEA(1,1);
  asm volatile("s_waitcnt vmcnt(6)" ::: "memory");
  BARRIER;

  #pragma unroll
  for (int I = 0; I < 7; ++I){
    const int e = 2*I;
    // P1: (buf0, M0,N0); stage B(e+1,0)
    READA(0,0); READB(0,0,b0); STAGEB(e+1, 0);
    BARRIER; MMA(0,0,b0); BARRIER;
    // P2: (M0,N1); stage A(e+2,0)
    READB(0,1,b1); STAGEA(e+2, 0);
    BARRIER; MMA(0,1,b1); BARRIER;
    // P3: (M1,N1); stage B(e+2,1)
    READA(0,1); STAGEB(e+2, 1);
    BARRIER; MMA(1,1,b1); BARRIER;
    // P4: (M1,N0); stage A(e+2,1); vmcnt(6)
    STAGEA(e+2, 1);
    asm volatile("s_waitcnt vmcnt(6)" ::: "memory");
    BARRIER; MMA(1,0,b0); BARRIER;
    // P5: (buf1, M0,N0); stage B(e+2,0)
    READA(1,0); READB(1,0,b0); STAGEB(e+2, 0);
    BARRIER; MMA(0,0,b0); BARRIER;
    // P6: (M0,N1); stage A(e+3,0)
    READB(1,1,b1); STAGEA(e+3, 0);
    BARRIER; MMA(0,1,b1); BARRIER;
    // P7: (M1,N1); stage B(e+3,1)
    READA(1,1); STAGEB(e+3, 1);
    BARRIER; MMA(1,1,b1); BARRIER;
    // P8: (M1,N0); stage A(e+3,1); vmcnt(6)
    STAGEA(e+3, 1);
    asm volatile("s_waitcnt vmcnt(6)" ::: "memory");
    BARRIER; MMA(1,0,b0); BARRIER;
  }

  { // ---- epilogue: K-tiles 14 (buf0) and 15 (buf1); only B(15,0) left to stage
    READA(0,0); READB(0,0,b0); STAGEB(15, 0);
    BARRIER; MMA(0,0,b0); BARRIER;
    READB(0,1,b1);
    BARRIER; MMA(0,1,b1); BARRIER;
    READA(0,1);
    BARRIER; MMA(1,1,b1); BARRIER;
    asm volatile("s_waitcnt vmcnt(0)" ::: "memory");
    BARRIER; MMA(1,0,b0); BARRIER;
    READA(1,0); READB(1,0,b0);
    BARRIER; MMA(0,0,b0); BARRIER;
    READB(1,1,b1);
    BARRIER; MMA(0,1,b1); BARRIER;
    READA(1,1);
    BARRIER; MMA(1,1,b1); BARRIER;
    MMA(1,0,b0);
  }

  // ---- C-write
  #pragma unroll
  for (int mh = 0; mh < 2; ++mh)
  #pragma unroll
  for (int f = 0; f < 4; ++f)
  #pragma unroll
  for (int nh = 0; nh < 2; ++nh)
  #pragma unroll
  for (int j = 0; j < 2; ++j){
    const int gcol = n0 + wn*64 + nh*32 + j*16 + l15;
    const float bi = bias[gcol];
    const int rbase = m0 + wm*128 + mh*64 + f*16 + l4*4;
    #pragma unroll
    for (int rr = 0; rr < 4; ++rr){
      const size_t idx = (size_t)(rbase + rr)*N + gcol;
      float v = acc[mh*4+f][nh*2+j][rr] + bi;
      if (EPI == 1) v += bf2f(resid16[idx]);
      Cout[idx] = f2bf(v);
    }
  }
}

// ---------------- per-(b,h) pooling kernel (512 threads, 8 waves) ----------------
// LDS-chunked: stage 1024-row chunks of the tensor into LDS once (swizzled),
// compute scores AND column accumulation from LDS, online softmax merge across chunks.
__device__ __forceinline__ float block_red_max512(float v, float* red, int tid){
  red[tid] = v; __syncthreads();
  for (int off = 256; off > 0; off >>= 1){
    if (tid < off) red[tid] = fmaxf(red[tid], red[tid+off]);
    __syncthreads();
  }
  float r = red[0]; __syncthreads();
  return r;
}
__device__ __forceinline__ float block_red_sum512(float v, float* red, int tid){
  red[tid] = v; __syncthreads();
  for (int off = 256; off > 0; off >>= 1){
    if (tid < off) red[tid] += red[tid+off];
    __syncthreads();
  }
  float r = red[0]; __syncthreads();
  return r;
}

// one tensor pass: ca[j] = sum_s softmax(score)_s * T[s][j] * (denominator kept in scal[1])
__device__ __forceinline__ void pool_pass(
    const uint16_t* __restrict__ base, const float* __restrict__ mrow,
    const float* __restrict__ wv, float biasv,
    uint16_t* qlds, float* sc, float* red, float (*part)[64],
    float* ca, float* scal, int tid, int wave, int lane)
{
  if (tid < 64) ca[tid] = 0.f;
  if (tid == 0){ scal[0] = -3.4e38f; scal[1] = 0.f; }
  __syncthreads();
  #pragma unroll
  for (int c = 0; c < 2; ++c){
    { // stage chunk c (1024 rows x 64 cols bf16) -> qlds, source-swizzled
      const int r8 = lane >> 3, sl = lane & 7;
      #pragma unroll
      for (int it = 0; it < 16; ++it){
        const int rowg = c*1024 + (wave*16 + it)*8 + r8;
        const uint16_t* src = base + (size_t)rowg*NQKV + ((sl ^ r8) << 3);
        __builtin_amdgcn_global_load_lds(AS1(src),
            AS3((char*)qlds + (wave*16 + it)*1024), 16, 0, 0);
      }
    }
    asm volatile("s_waitcnt vmcnt(0)" ::: "memory");
    __syncthreads();
    // scores for rows tid, tid+512 (chunk-local)
    #pragma unroll
    for (int rr = 0; rr < 2; ++rr){
      const int row = tid + rr*512;
      float acc = 0.f;
      #pragma unroll
      for (int jj = 0; jj < 8; ++jj){
        bf16x8 v = *(const bf16x8*)(qlds + row*64 + ((jj ^ (row & 7)) << 3));
        #pragma unroll
        for (int e = 0; e < 8; ++e) acc += (float)v[e] * wv[jj*8 + e];
      }
      sc[row] = (acc + biasv)*0.125f + mrow[c*1024 + row];
    }
    __syncthreads();
    const float lm = fmaxf(sc[tid], sc[tid+512]);
    const float mx = block_red_max512(lm, red, tid);
    const float e0 = __expf(sc[tid] - mx), e1 = __expf(sc[tid+512] - mx);
    sc[tid] = e0; sc[tid+512] = e1;
    const float lc = block_red_sum512(e0 + e1, red, tid);
    { // col accum: group g = wave handles rows [g*128, g*128+128)
      const int j = tid & 63, g = tid >> 6;
      const int slot_sh = j >> 3, jin = j & 7;
      float a = 0.f;
      for (int s = 0; s < 128; ++s){
        const int row = g*128 + s;
        a += sc[row] * bf2f(qlds[row*64 + (((slot_sh) ^ (row & 7)) << 3) + jin]);
      }
      part[g][j] = a;
    }
    __syncthreads();
    if (tid < 64){
      float colc = 0.f;
      #pragma unroll
      for (int g2 = 0; g2 < 8; ++g2) colc += part[g2][tid];
      const float m_old = scal[0], l_old = scal[1];
      const float m_new = fmaxf(m_old, mx);
      const float fo = __expf(m_old - m_new), fc = __expf(mx - m_new);
      ca[tid] = ca[tid]*fo + colc*fc;
      if (tid == 0){ scal[1] = l_old*fo + lc*fc; scal[0] = m_new; }
    }
    __syncthreads();
  }
}

__global__ __launch_bounds__(512)
void k_head(const uint16_t* __restrict__ qkv, const float* __restrict__ mask,
            const float* __restrict__ wa, const float* __restrict__ ba,
            const float* __restrict__ wb, const float* __restrict__ bbp,
            const float* __restrict__ Wu, uint16_t* __restrict__ WuPT)
{
  __shared__ uint16_t qlds[1024*64];   // 128 KB chunk
  __shared__ float sc[1024];
  __shared__ float red[512];
  __shared__ float part[8][64];
  __shared__ float ca[64];
  __shared__ float qav[64], wvec[64], wva[64], pav[64];
  __shared__ float scal[2];

  const int bh = blockIdx.x, b = bh >> 4, h = bh & 15;
  const int tid = threadIdx.x, wave = tid >> 6, lane = tid & 63;
  const uint16_t* qb  = qkv + (size_t)b*SS*NQKV + h*64;
  const uint16_t* kb2 = qb + 1024;
  const float* mrow = mask + b*SS;

  if (tid < 64) wva[tid] = wa[tid];
  __syncthreads();

  // ---- alpha over q ----
  pool_pass(qb, mrow, wva, ba[0], qlds, sc, red, part, ca, scal, tid, wave, lane);
  if (tid < 64){
    const float qv = ca[tid] / scal[1];
    qav[tid] = qv;
    wvec[tid] = qv * wb[tid];
  }
  __syncthreads();

  // ---- beta over k (gated by q_av folded into the probe vector) ----
  pool_pass(kb2, mrow, wvec, bbp[0], qlds, sc, red, part, ca, scal, tid, wave, lane);
  if (tid < 64) pav[tid] = qav[tid] * (ca[tid] / scal[1]);
  __syncthreads();

  // WuPT[j][i] = pav[i]*Wu[i][j]   (bf16, n-major for MFMA B operand)
  uint16_t* dst = WuPT + (size_t)bh*4096;
  for (int idx = tid; idx < 4096; idx += 512){
    const int i = idx & 63, jcol = idx >> 6;
    dst[idx] = f2bf(pav[i]*Wu[i*64 + jcol]);
  }
}

// ---------------- newr = v @ WuP + bu + q   (per-head MFMA) ----------------
__global__ __launch_bounds__(256)
void k_newr(const uint16_t* __restrict__ qkv, const uint16_t* __restrict__ WuPT,
            const float* __restrict__ bu, uint16_t* __restrict__ newr)
{
  const int bh = blockIdx.x >> 3, st = blockIdx.x & 7;
  const int b = bh >> 4, h = bh & 15;
  const int tid = threadIdx.x, wave = tid >> 6, lane = tid & 63;
  const int l15 = lane & 15, l4 = lane >> 4;
  const int s0 = st*256 + wave*64;
  const uint16_t* vb = qkv + 2048 + h*64;
  const uint16_t* wt = WuPT + (size_t)bh*4096;

  f32x4 acc[4][4] = {};
  #pragma unroll
  for (int ks = 0; ks < 2; ++ks){
    bf16x8 bfr[4];
    #pragma unroll
    for (int n = 0; n < 4; ++n)
      bfr[n] = *(const bf16x8*)(wt + (n*16 + l15)*64 + ks*32 + l4*8);
    #pragma unroll
    for (int m = 0; m < 4; ++m){
      const int s = s0 + m*16 + l15;
      bf16x8 af = *(const bf16x8*)(vb + (size_t)(b*SS + s)*NQKV + ks*32 + l4*8);
      #pragma unroll
      for (int n = 0; n < 4; ++n)
        acc[m][n] = __builtin_amdgcn_mfma_f32_16x16x32_bf16(af, bfr[n], acc[m][n], 0, 0, 0);
    }
  }
  #pragma unroll
  for (int n = 0; n < 4; ++n){
    const int j = n*16 + l15;
    const float bj = bu[j];
    #pragma unroll
    for (int m = 0; m < 4; ++m){
      #pragma unroll
      for (int r = 0; r < 4; ++r){
        const int s = s0 + m*16 + l4*4 + r;
        const size_t qidx = (size_t)(b*SS + s)*NQKV + h*64 + j;
        const float q = bf2f(qkv[qidx]);
        newr[(size_t)(b*SS + s)*DD + h*64 + j] = f2bf(acc[m][n][r] + bj + q);
      }
    }
  }
}

// ---------------- layernorm (bf16 input h, f32 output) ----------------
__global__ __launch_bounds__(256)
void k_ln(const uint16_t* __restrict__ h16, const float* __restrict__ gamma,
          const float* __restrict__ beta, float* __restrict__ out)
{
  __shared__ float r1[256], r2[256];
  const int row = blockIdx.x, tid = threadIdx.x;
  const ushort4 hv = ((const ushort4*)(h16 + (size_t)row*DD))[tid];
  float v0 = bf2f(hv.x), v1 = bf2f(hv.y), v2 = bf2f(hv.z), v3 = bf2f(hv.w);
  float s  = v0 + v1 + v2 + v3;
  float ss = v0*v0 + v1*v1 + v2*v2 + v3*v3;
  r1[tid] = s; r2[tid] = ss; __syncthreads();
  for (int off = 128; off > 0; off >>= 1){
    if (tid < off){ r1[tid] += r1[tid+off]; r2[tid] += r2[tid+off]; }
    __syncthreads();
  }
  const float mu  = r1[0]*(1.f/1024.f);
  const float var = r2[0]*(1.f/1024.f) - mu*mu;
  const float inv = rsqrtf(var + 1e-6f);
  const float4 g  = ((const float4*)gamma)[tid];
  const float4 be = ((const float4*)beta)[tid];
  float4 o;
  o.x = (v0-mu)*inv*g.x + be.x;
  o.y = (v1-mu)*inv*g.y + be.y;
  o.z = (v2-mu)*inv*g.z + be.z;
  o.w = (v3-mu)*inv*g.w + be.w;
  ((float4*)(out + (size_t)row*DD))[tid] = o;
}

// ---------------- launch ----------------
extern "C" void kernel_launch(void* const* d_in, const int* in_sizes, int n_in,
                              void* d_out, int out_size, void* d_ws, size_t ws_size,
                              hipStream_t stream) {
  const float* x    = (const float*)d_in[0];
  const float* mask = (const float*)d_in[1];
  const float* Wq   = (const float*)d_in[2];
  const float* bq   = (const float*)d_in[3];
  const float* Wk   = (const float*)d_in[4];
  const float* bk   = (const float*)d_in[5];
  const float* Wv   = (const float*)d_in[6];
  const float* bv   = (const float*)d_in[7];
  const float* wa   = (const float*)d_in[8];
  const float* ba   = (const float*)d_in[9];
  const float* wb   = (const float*)d_in[10];
  const float* bb   = (const float*)d_in[11];
  const float* Wu   = (const float*)d_in[12];
  const float* bu   = (const float*)d_in[13];
  const float* Wo   = (const float*)d_in[14];
  const float* bo   = (const float*)d_in[15];
  const float* gamma= (const float*)d_in[16];
  const float* beta = (const float*)d_in[17];
  float* out = (float*)d_out;

  char* ws = (char*)d_ws;
  const size_t MB = 1ull << 20;
  uint16_t* xb    = (uint16_t*)(ws);              // 32 MB [16384][1024] bf16
  uint16_t* Wt    = (uint16_t*)(ws + 32*MB);      // 6 MB  [3072][1024]  bf16
  uint16_t* WoT   = (uint16_t*)(ws + 38*MB);      // 2 MB  [1024][1024]  bf16
  float*    bqkv  = (float*)   (ws + 40*MB);      // 12 KB
  uint16_t* WuPT  = (uint16_t*)(ws + 41*MB);      // 1 MB  [128][64][64] bf16
  uint16_t* qkv   = (uint16_t*)(ws + 42*MB);      // 96 MB [16384][3072] bf16
  uint16_t* newr  = (uint16_t*)(ws + 138*MB);     // 32 MB [16384][1024] bf16
  uint16_t* hbuf16= (uint16_t*)(ws + 42*MB);      // 32 MB, aliases dead qkv

  k_prep<<<6156, 256, 0, stream>>>(x, Wq, Wk, Wv, Wo, bq, bk, bv, xb, Wt, WoT, bqkv);

  k_gemm256<0,12><<<(MTOT/256)*(NQKV/256), 512, 0, stream>>>(xb, Wt, bqkv, nullptr, qkv);
  k_head<<<BB*HH, 512, 0, stream>>>(qkv, mask, wa, ba, wb, bb, Wu, WuPT);
  k_newr<<<BB*HH*8, 256, 0, stream>>>(qkv, WuPT, bu, newr);
  k_gemm256<1,4><<<(MTOT/256)*(DD/256), 512, 0, stream>>>(newr, WoT, bo, xb, hbuf16);
  k_ln<<<MTOT, 256, 0, stream>>>(hbuf16, gamma, beta, out);
}